// Round 2
// baseline (500.377 us; speedup 1.0000x reference)
//
#include <hip/hip_runtime.h>
#include <hip/hip_fp16.h>
#include <math.h>

// Problem: PREDICT_EMISSION_3D_GRID_48155173323452
// R3: R1 (passing, 221us pe_main, VALUBusy=100%) spent ~85% of its VALU ops
// in libm sincosf (Payne-Hanek + divergent slow path). R2's raw
// __builtin_amdgcn_sinf swap failed correctness (absmax 0.307) -> do not
// trust the raw intrinsic. This round: EXACT R1 kernel with ONLY the trig
// replaced by explicit revolution reduction + in-house Taylor(15/14) sin/cos
// on [-pi,pi) — ~21 full-rate VALU ops, fully-owned IEEE semantics, NaN
// propagates identically (theta=inf -> fr=NaN -> poly NaN -> isfinite mask).
// Reduction error: dtheta ~ theta*7e-7 -> displacement r*dtheta =
// m*r^{-1/2}*7e-7 <= 2e-5 for the worst sample; poly abs err <= ~4e-6.

#define GR 64

// One-thread setup: unit rotation axis + m = -t*v into ws[0..3].
__global__ void pe_setup(const float* __restrict__ gt, const float* __restrict__ gv,
                         const float* __restrict__ gax, float* __restrict__ ws)
{
    if (threadIdx.x == 0 && blockIdx.x == 0) {
        float t = gt[0], v = gv[0];
        float ax = gax[0], ay = gax[1], az = gax[2];
        float anorm = sqrtf(ax * ax + ay * ay + az * az);
        ws[0] = ax / anorm;
        ws[1] = ay / anorm;
        ws[2] = az / anorm;
        ws[3] = (-t) * v;
    }
}

// Build B[ix][iy][iz] = 8 fp16 corner values {G[x+dx][y+dy][z+dz]}, dx,dy,dz in {0,1},
// neighbor indices clamped to 63 (entries needing the clamp are only read with zero
// weight or never read: main kernel bases are <= 62 per dim).
__global__ __launch_bounds__(256) void pe_build(const float* __restrict__ g,
                                                uint4* __restrict__ table)
{
    const int idx = blockIdx.x * 256 + threadIdx.x;
    if (idx >= GR * GR * GR) return;
    const int iz = idx & 63, iy = (idx >> 6) & 63, ix = idx >> 12;
    const int z1 = min(iz + 1, 63), y1 = min(iy + 1, 63), x1 = min(ix + 1, 63);
    const float* p00 = g + (ix * GR + iy) * GR;
    const float* p01 = g + (ix * GR + y1) * GR;
    const float* p10 = g + (x1 * GR + iy) * GR;
    const float* p11 = g + (x1 * GR + y1) * GR;
    __half2 h0 = __floats2half2_rn(p00[iz], p00[z1]);   // (x0,y0,z0),(x0,y0,z1)
    __half2 h1 = __floats2half2_rn(p01[iz], p01[z1]);   // (x0,y1,*)
    __half2 h2 = __floats2half2_rn(p10[iz], p10[z1]);   // (x1,y0,*)
    __half2 h3 = __floats2half2_rn(p11[iz], p11[z1]);   // (x1,y1,*)
    uint4 q;
    q.x = *(const unsigned int*)&h0;
    q.y = *(const unsigned int*)&h1;
    q.z = *(const unsigned int*)&h2;
    q.w = *(const unsigned int*)&h3;
    table[idx] = q;
}

// Per-dim: given i0 (=floor voxel), produce base b in [0,62] and weights (wA,wB)
// for table slots (b, b+1), with jax constant-mode zeroing. i0c,i1c always lie
// in {b, b+1}, so the remap is exact.  (R1 version, verbatim.)
__device__ __forceinline__ void dim_weights(float c, int& b, float& wA, float& wB)
{
    const float f = floorf(c);
    const int i0 = (int)f;
    const int i1 = i0 + 1;
    float w1 = c - f;
    float w0 = 1.0f - w1;
    const int i0c = min(max(i0, 0), GR - 1);
    const int i1c = min(max(i1, 0), GR - 1);
    b = min(max(i0, 0), GR - 2);
    w0 = (i0c == i0) ? w0 : 0.0f;   // zero weight if corner was OOB
    w1 = (i1c == i1) ? w1 : 0.0f;
    wA = ((i0c == b) ? w0 : 0.0f) + ((i1c == b) ? w1 : 0.0f);
    wB = (w0 + w1) - wA;            // each weight lands on exactly one slot
}

__global__ __launch_bounds__(256) void pe_main(
    const float* __restrict__ gx, const float* __restrict__ gy, const float* __restrict__ gz,
    const uint4* __restrict__ table, const float* __restrict__ kws,
    float* __restrict__ out, int n4)
{
    const int tid = blockIdx.x * 256 + threadIdx.x;
    if (tid >= n4) return;

    const float kx = kws[0], ky = kws[1], kz = kws[2], m = kws[3];

    const float4 X = ((const float4*)gx)[tid];
    const float4 Y = ((const float4*)gy)[tid];
    const float4 Z = ((const float4*)gz)[tid];
    const float xs[4] = {X.x, X.y, X.z, X.w};
    const float ys[4] = {Y.x, Y.y, Y.z, Y.w};
    const float zs[4] = {Z.x, Z.y, Z.z, Z.w};
    float4 Rv;
    float* rp = &Rv.x;

#pragma unroll
    for (int j = 0; j < 4; ++j) {
        const float px = xs[j], py = ys[j], pz = zs[j];

        // theta = m * r^{-1.5}; r=0 -> inf -> NaN after trig (masked below)
        const float r2 = px * px + py * py + pz * pz;
        const float r = sqrtf(r2);
        const float theta = m * rsqrtf(r2 * r);

        // --- R3 trig: reduce to a = (theta mod 2pi) - pi in [-pi, pi), then
        // Taylor(15/14). sin(theta) = -sin(a), cos(theta) = -cos(a).
        // theta = +-inf/NaN -> fr = NaN -> st,ct NaN (matches reference mask).
        const float tr = theta * 0.15915494309189535f;   // theta / (2*pi)
        const float fr = tr - floorf(tr);                // frac, in [0,1); exact sub
        const float u  = fr - 0.5f;                      // [-0.5, 0.5), exact
        const float a  = u * 6.283185307179586f;         // [-pi, pi)
        const float t2 = a * a;

        float sp = -7.6471637e-13f;                      // a^15/15! term
        sp = fmaf(sp, t2, 1.6059044e-10f);               // 1/13!
        sp = fmaf(sp, t2, -2.5052108e-8f);               // -1/11!
        sp = fmaf(sp, t2, 2.7557319e-6f);                // 1/9!
        sp = fmaf(sp, t2, -1.9841270e-4f);               // -1/7!
        sp = fmaf(sp, t2, 8.3333333e-3f);                // 1/5!
        sp = fmaf(sp, t2, -1.6666667e-1f);               // -1/3!
        sp = fmaf(sp, t2, 1.0f);
        const float st = -(a * sp);                      // sin(theta)

        float cp = -1.1470746e-11f;                      // -1/14!
        cp = fmaf(cp, t2, 2.0876757e-9f);                // 1/12!
        cp = fmaf(cp, t2, -2.7557319e-7f);               // -1/10!
        cp = fmaf(cp, t2, 2.4801587e-5f);                // 1/8!
        cp = fmaf(cp, t2, -1.3888889e-3f);               // -1/6!
        cp = fmaf(cp, t2, 4.1666667e-2f);                // 1/4!
        cp = fmaf(cp, t2, -5.0e-1f);                     // -1/2!
        cp = fmaf(cp, t2, 1.0f);
        const float ct = -cp;                            // cos(theta)
        // --- end R3 trig

        const float omc = 1.0f - ct;
        const float kdp = px * kx + py * ky + pz * kz;

        float nx = px * ct + (ky * pz - kz * py) * st + kx * kdp * omc;
        float ny = py * ct + (kz * px - kx * pz) * st + ky * kdp * omc;
        float nz = pz * ct + (kx * py - ky * px) * st + kz * kdp * omc;

        const bool fv0 = isfinite(nx);
        nx = fv0 ? nx : 0.0f;
        ny = isfinite(ny) ? ny : 0.0f;
        nz = isfinite(nz) ? nz : 0.0f;

        const float cx = (nx + 5.0f) / 10.0f * 63.0f;
        const float cy = (ny + 5.0f) / 10.0f * 63.0f;
        const float cz = (nz + 5.0f) / 10.0f * 63.0f;

        int bx, by, bz;
        float wxA, wxB, wyA, wyB, wzA, wzB;
        dim_weights(cx, bx, wxA, wxB);
        dim_weights(cy, by, wyA, wyB);
        dim_weights(cz, bz, wzA, wzB);

        const uint4 q = table[(bx << 12) | (by << 6) | bz];   // ONE 16-B probe
        const float2 a0 = __half22float2(*(const __half2*)&q.x);  // (x0,y0,z0/z1)
        const float2 a1 = __half22float2(*(const __half2*)&q.y);  // (x0,y1,*)
        const float2 a2 = __half22float2(*(const __half2*)&q.z);  // (x1,y0,*)
        const float2 a3 = __half22float2(*(const __half2*)&q.w);  // (x1,y1,*)

        const float z00 = wzA * a0.x + wzB * a0.y;
        const float z01 = wzA * a1.x + wzB * a1.y;
        const float z10 = wzA * a2.x + wzB * a2.y;
        const float z11 = wzA * a3.x + wzB * a3.y;

        const float em = wxA * (wyA * z00 + wyB * z01) + wxB * (wyA * z10 + wyB * z11);
        rp[j] = fv0 ? em : 0.0f;
    }

    ((float4*)out)[tid] = Rv;
}

extern "C" void kernel_launch(void* const* d_in, const int* in_sizes, int n_in,
                              void* d_out, int out_size, void* d_ws, size_t ws_size,
                              hipStream_t stream)
{
    const float* gx   = (const float*)d_in[0];
    const float* gy   = (const float*)d_in[1];
    const float* gz   = (const float*)d_in[2];
    const float* gt   = (const float*)d_in[3];
    const float* gv   = (const float*)d_in[4];
    const float* gax  = (const float*)d_in[5];
    const float* grid = (const float*)d_in[6];
    float* out = (float*)d_out;

    float* ws_params = (float*)d_ws;                        // 16 B params
    uint4* table = (uint4*)((char*)d_ws + 256);             // 4 MB corner-cube table

    const int n  = out_size;     // 33554432, divisible by 4
    const int n4 = n >> 2;

    pe_setup<<<1, 64, 0, stream>>>(gt, gv, gax, ws_params);
    pe_build<<<(GR * GR * GR) / 256, 256, 0, stream>>>(grid, table);
    pe_main<<<(n4 + 255) / 256, 256, 0, stream>>>(gx, gy, gz, table, ws_params, out, n4);
}